// Round 10
// baseline (128.466 us; speedup 1.0000x reference)
//
#include <hip/hip_runtime.h>
#include <hip/hip_bf16.h>
#include <math.h>

#define NB 4096   // batch
#define ND 2048   // feature dim
#define BT 256    // output tile (256x256)
#define NTB (NB / BT)     // 16 tile-blocks per dim
#define NKT (ND / 32)     // 64 K-tiles of 32
#define TP 136            // transposed-pack padded row (ushorts)

typedef __attribute__((ext_vector_type(8))) short short8;
typedef __attribute__((ext_vector_type(4))) float floatx4;
typedef __attribute__((ext_vector_type(4))) unsigned short ushort4v;

#define GLOAD_LDS16(g, l) \
  __builtin_amdgcn_global_load_lds((const __attribute__((address_space(1))) void*)(g), \
                                   (__attribute__((address_space(3))) void*)(l), 16, 0, 0)

// order-preserving float<->uint encode (min/max via unsigned atomics)
__device__ __forceinline__ unsigned fenc(float f) {
  unsigned u = __float_as_uint(f);
  return (u >> 31) ? ~u : (u | 0x80000000u);
}
__device__ __forceinline__ float fdec(unsigned u) {
  unsigned b = (u & 0x80000000u) ? (u ^ 0x80000000u) : ~u;
  return __uint_as_float(b);
}

__device__ __forceinline__ unsigned f2bf(float x) {  // RNE fp32 -> bf16 bits
  unsigned u = __float_as_uint(x);
  return (u + 0x7FFFu + ((u >> 16) & 1u)) >> 16;
}

union H16 { unsigned short u; _Float16 h; };
__device__ __forceinline__ unsigned short f2h(float x) { H16 c; c.h = (_Float16)x; return c.u; }
__device__ __forceinline__ float h2f(unsigned short u) { H16 c; c.u = u; return (float)c.h; }

// ---- kernel 1: L2-normalize rows -> bf16; init min/max sentinels ----
__global__ __launch_bounds__(256) void norm_kernel(const float* __restrict__ feats,
                                                   unsigned short* __restrict__ fb,
                                                   unsigned* __restrict__ gpm,
                                                   unsigned* __restrict__ gnm) {
  int row = blockIdx.x;
  int t = threadIdx.x;
  if (t == 0) {
    gpm[row] = 0xFFFFFFFFu;  // decodes NaN -> masks false (empty-min semantics)
    gnm[row] = 0u;
  }
  const float4* src = (const float4*)(feats + (size_t)row * ND);
  float4 v0 = src[t * 2];
  float4 v1 = src[t * 2 + 1];
  float ss = v0.x * v0.x + v0.y * v0.y + v0.z * v0.z + v0.w * v0.w +
             v1.x * v1.x + v1.y * v1.y + v1.z * v1.z + v1.w * v1.w;
  for (int off = 32; off > 0; off >>= 1) ss += __shfl_down(ss, off);
  __shared__ float wsum[4];
  int lane = t & 63, wid = t >> 6;
  if (lane == 0) wsum[wid] = ss;
  __syncthreads();
  float tot = wsum[0] + wsum[1] + wsum[2] + wsum[3];
  float inv = 1.0f / (sqrtf(tot) + 1e-12f);
  uint4 o;
  o.x = f2bf(v0.x * inv) | (f2bf(v0.y * inv) << 16);
  o.y = f2bf(v0.z * inv) | (f2bf(v0.w * inv) << 16);
  o.z = f2bf(v1.x * inv) | (f2bf(v1.y * inv) << 16);
  o.w = f2bf(v1.z * inv) | (f2bf(v1.w * inv) << 16);
  ((uint4*)(fb + (size_t)row * ND))[t] = o;
}

// ---- kernel 2: 256x256-tile 8-wave GEMM; BK=32, 3-deep, 1 barrier/tile ----
__global__ __launch_bounds__(512, 2) void pass0_kernel(const unsigned short* __restrict__ fb,
                                                       const int* __restrict__ labels,
                                                       unsigned* __restrict__ gpm,
                                                       unsigned* __restrict__ gnm,
                                                       unsigned short* __restrict__ sim) {
  // 3 slots x (A 16KB + B 16KB) = 96KB; epilogue pack reuses region
  __shared__ __align__(16) char shraw[98304];
  __shared__ int rowlab[BT], collab[BT];

  int tid = threadIdx.x;
  int l = tid & 63, wv = tid >> 6;
  int wm = wv >> 2, wn = wv & 3;   // 2 x 4 wave grid

  // XCD clustering: each XCD owns a 4(bi) x 8(bj) rectangle
  int bid = blockIdx.x;
  int xcd = bid & 7, li_ = bid >> 3;
  int bi = (xcd >> 1) * 4 + (li_ >> 3);
  int bj = (xcd & 1) * 8 + (li_ & 7);
  int row0 = bi * BT, col0 = bj * BT;

  char* A0p = shraw;
  char* B0p = shraw + 16384;
  char* A1p = shraw + 32768;
  char* B1p = shraw + 49152;
  char* A2p = shraw + 65536;
  char* B2p = shraw + 81920;

  // stage one full 256x32 A-tile + B-tile into slot (4 gloads/thread):
  // linear LDS dest, inverse-swizzled global source (chunk ^= (r^(r>>2))&3)
  auto stageT = [&](char* SA, char* SB, int ts) {
#pragma unroll
    for (int e = 0; e < 2; e++) {
      int li = (wv * 2 + e) * 64 + l;        // 0..1023
      int r_ = li >> 2, c_ = li & 3;
      int gk = ts * 32 + ((c_ ^ ((r_ ^ (r_ >> 2)) & 3)) * 8);
      GLOAD_LDS16(fb + (size_t)(row0 + r_) * ND + gk, SA + li * 16);
      GLOAD_LDS16(fb + (size_t)(col0 + r_) * ND + gk, SB + li * 16);
    }
  };

  floatx4 acc[8][4];
#pragma unroll
  for (int j = 0; j < 8; j++)
#pragma unroll
    for (int r = 0; r < 4; r++) acc[j][r] = (floatx4){0.f, 0.f, 0.f, 0.f};

  // per-lane LDS byte offsets (row stride 64B; swizzled chunk)
  int offA[8], offB[4];
  {
    int ck = l >> 4;
#pragma unroll
    for (int j = 0; j < 8; j++) {
      int rh = (2 * j + wm) * 16 + (l & 15);
      offA[j] = rh * 64 + ((ck ^ ((rh ^ (rh >> 2)) & 3)) * 16);
    }
#pragma unroll
    for (int r = 0; r < 4; r++) {
      int rh = (wn + 4 * r) * 16 + (l & 15);
      offB[r] = rh * 64 + ((ck ^ ((rh ^ (rh >> 2)) & 3)) * 16);
    }
  }

  // clean vmcnt ledger: labels drained before any stage
  if (tid < BT) {
    rowlab[tid] = labels[row0 + tid];
    collab[tid] = labels[col0 + tid];
  }
  asm volatile("s_waitcnt vmcnt(0) lgkmcnt(0)" ::: "memory");
  __builtin_amdgcn_s_barrier();

  // prologue: tiles 0,1 staged; retire tile0 (leave tile1's 4 in flight)
  stageT(A0p, B0p, 0);
  stageT(A1p, B1p, 1);
  asm volatile("s_waitcnt vmcnt(4)" ::: "memory");
  __builtin_amdgcn_s_barrier();

  // per tile: stage(u+2) -> 12 ds_reads -> lgkm(0) -> 32 MFMA -> vmcnt -> barrier
#define TILE(AP, BP, SAP, SBP, TS, DO_ST, DO_VM, VMS)                             \
  {                                                                               \
    if (DO_ST) stageT((SAP), (SBP), (TS));                                        \
    short8 a_[8], b_[4];                                                          \
    _Pragma("unroll") for (int j = 0; j < 8; j++)                                 \
      a_[j] = *(const short8*)((AP) + offA[j]);                                   \
    _Pragma("unroll") for (int r = 0; r < 4; r++)                                 \
      b_[r] = *(const short8*)((BP) + offB[r]);                                   \
    asm volatile("s_waitcnt lgkmcnt(0)" ::: "memory");                            \
    __builtin_amdgcn_sched_barrier(0);                                            \
    __builtin_amdgcn_s_setprio(1);                                                \
    _Pragma("unroll") for (int j = 0; j < 8; j++)                                 \
      _Pragma("unroll") for (int r = 0; r < 4; r++)                               \
        acc[j][r] = __builtin_amdgcn_mfma_f32_16x16x32_bf16(a_[j], b_[r],         \
                                                            acc[j][r], 0, 0, 0);  \
    __builtin_amdgcn_s_setprio(0);                                                \
    if (DO_VM) asm volatile("s_waitcnt vmcnt(" VMS ")" ::: "memory");             \
    __builtin_amdgcn_s_barrier();                                                 \
  }

  for (int u = 0; u < NKT - 4; u += 3) {
    TILE(A0p, B0p, A2p, B2p, u + 2, true, true, "4")
    TILE(A1p, B1p, A0p, B0p, u + 3, true, true, "4")
    TILE(A2p, B2p, A1p, B1p, u + 4, true, true, "4")
  }
  // u = 60, 61 stage the last tiles; 62 drains; 63 bare
  TILE(A0p, B0p, A2p, B2p, 62, true, true, "4")
  TILE(A1p, B1p, A0p, B0p, 63, true, true, "4")
  TILE(A2p, B2p, A0p, B0p, 0, false, true, "0")
  TILE(A0p, B0p, A0p, B0p, 0, false, false, "0")

  // ---- row-attributed stats from registers ----
  // C/D layout: col = lane&15, row = (lane>>4)*4 + v; frag row = (2j+wm)*16
#pragma unroll
  for (int j = 0; j < 8; j++) {
#pragma unroll
    for (int v = 0; v < 4; v++) {
      int row_l = (2 * j + wm) * 16 + (l >> 4) * 4 + v;
      int grow = row0 + row_l;
      int rl = rowlab[row_l];
      float pmin = 3.0e38f, nmax = -3.0e38f;
#pragma unroll
      for (int r = 0; r < 4; r++) {
        int col_l = (wn + 4 * r) * 16 + (l & 15);
        float s = acc[j][r][v];
        if (rl == collab[col_l]) {
          if ((col0 + col_l) != grow && s < 0.99999f) pmin = fminf(pmin, s);
        } else {
          nmax = fmaxf(nmax, s);
        }
      }
#pragma unroll
      for (int off = 1; off < 16; off <<= 1) {
        pmin = fminf(pmin, __shfl_xor(pmin, off));
        nmax = fmaxf(nmax, __shfl_xor(nmax, off));
      }
      if ((l & 15) == 0) {
        atomicMin(&gpm[grow], fenc(pmin));  // sentinels encode harmless
        atomicMax(&gnm[grow], fenc(nmax));
      }
    }
  }

  // ---- transposed fp16 pack + coalesced store (sim symmetric; 2 row-halves) ----
#pragma unroll
  for (int h = 0; h < 2; h++) {
    __syncthreads();  // previous LDS use done
    unsigned short (*tileT)[TP] = (unsigned short(*)[TP])shraw;
#pragma unroll
    for (int jl = 0; jl < 4; jl++) {
      int j = h * 4 + jl;
      int lr = (2 * jl + wm) * 16 + (l >> 4) * 4;  // local row within half
#pragma unroll
      for (int r = 0; r < 4; r++) {
        int C = (wn + 4 * r) * 16 + (l & 15);
        ushort4v pk;
        pk[0] = f2h(acc[j][r][0]);
        pk[1] = f2h(acc[j][r][1]);
        pk[2] = f2h(acc[j][r][2]);
        pk[3] = f2h(acc[j][r][3]);
        *(ushort4v*)(&tileT[C][lr]) = pk;
      }
    }
    __syncthreads();
    int c = tid >> 1, seg = tid & 1;
    const unsigned short* srcp = &tileT[c][seg * 64];
    unsigned short* dstp = sim + (size_t)(col0 + c) * NB + row0 + h * 128 + seg * 64;
#pragma unroll
    for (int k = 0; k < 8; k++)
      *(short8*)(dstp + k * 8) = *(const short8*)(srcp + k * 8);
  }
}

// ---- kernel 3: streaming masked exp-sums, one wave per row ----
__global__ __launch_bounds__(256) void sums_kernel(const unsigned short* __restrict__ sim,
                                                   const int* __restrict__ labels,
                                                   const unsigned* __restrict__ gpm,
                                                   const unsigned* __restrict__ gnm,
                                                   float* __restrict__ gps,
                                                   float* __restrict__ gns) {
  int t = threadIdx.x, l = t & 63, w = t >> 6;
  int r = blockIdx.x * 4 + w;
  int rl = labels[r];
  float pm = fdec(gpm[r]);  // pos_min (NaN if none -> masks false)
  float nm = fdec(gnm[r]);  // neg_max
  const unsigned short* row = sim + (size_t)r * NB;
  float ps0 = 0.f, ps1 = 0.f, ns0 = 0.f, ns1 = 0.f;
#pragma unroll
  for (int it = 0; it < 8; it++) {
    int j0 = it * 512 + l * 8;
    short8 sv = *(const short8*)(row + j0);
    int4 lb0 = *(const int4*)(labels + j0);
    int4 lb1 = *(const int4*)(labels + j0 + 4);
    int lb[8] = {lb0.x, lb0.y, lb0.z, lb0.w, lb1.x, lb1.y, lb1.z, lb1.w};
#pragma unroll
    for (int e = 0; e < 8; e++) {
      float s = h2f((unsigned short)sv[e]);
      int j = j0 + e;
      float pv = 0.f, nv = 0.f;
      if (lb[e] == rl) {
        if (j != r && s < 0.99999f && (s - 0.1f < nm)) pv = __expf(-2.0f * (s - 0.5f));
      } else {
        if (s + 0.1f > pm) nv = __expf(40.0f * (s - 0.5f));
      }
      if (e & 1) { ps1 += pv; ns1 += nv; }
      else       { ps0 += pv; ns0 += nv; }
    }
  }
  float ps = ps0 + ps1, ns = ns0 + ns1;
  for (int off = 32; off > 0; off >>= 1) {
    ps += __shfl_down(ps, off);
    ns += __shfl_down(ns, off);
  }
  if (l == 0) { gps[r] = ps; gns[r] = ns; }
}

// ---- kernel 4: finalize scalar loss ----
__global__ __launch_bounds__(256) void finalize_kernel(const float* __restrict__ gps,
                                                       const float* __restrict__ gns,
                                                       float* __restrict__ out) {
  int t = threadIdx.x;
  float sum = 0.f;
  for (int i = t; i < NB; i += 256) {
    float ps = gps[i], ns = gns[i];
    if (ps > 0.f && ns > 0.f) sum += 0.5f * log1pf(ps) + 0.025f * log1pf(ns);
  }
  for (int off = 32; off > 0; off >>= 1) sum += __shfl_down(sum, off);
  __shared__ float wsum[4];
  int lane = t & 63, wid = t >> 6;
  if (lane == 0) wsum[wid] = sum;
  __syncthreads();
  if (t == 0) out[0] = (wsum[0] + wsum[1] + wsum[2] + wsum[3]) / (float)NB;
}

extern "C" void kernel_launch(void* const* d_in, const int* in_sizes, int n_in,
                              void* d_out, int out_size, void* d_ws, size_t ws_size,
                              hipStream_t stream) {
  const float* feats = (const float*)d_in[0];
  const int* labels = (const int*)d_in[1];

  char* ws = (char*)d_ws;
  unsigned short* fb = (unsigned short*)ws;                  // 16 MB bf16 normalized feats
  size_t off = (size_t)NB * ND * 2;
  unsigned short* sim = (unsigned short*)(ws + off);         // 32 MB fp16 sim (full)
  off += (size_t)NB * NB * 2;
  unsigned* gpm = (unsigned*)(ws + off); off += NB * 4;
  unsigned* gnm = (unsigned*)(ws + off); off += NB * 4;
  float* gps = (float*)(ws + off); off += NB * 4;
  float* gns = (float*)(ws + off); off += NB * 4;

  norm_kernel<<<NB, 256, 0, stream>>>(feats, fb, gpm, gnm);
  pass0_kernel<<<NTB * NTB, 512, 0, stream>>>(fb, labels, gpm, gnm, sim);
  sums_kernel<<<NB / 4, 256, 0, stream>>>(sim, labels, gpm, gnm, gps, gns);
  finalize_kernel<<<1, 256, 0, stream>>>(gps, gns, (float*)d_out);
}